// Round 7
// baseline (260.644 us; speedup 1.0000x reference)
//
#include <hip/hip_runtime.h>
#include <stdint.h>

typedef __attribute__((ext_vector_type(8))) short short8;
typedef __attribute__((ext_vector_type(4))) float f32x4;
typedef __attribute__((ext_vector_type(8))) unsigned short u16x8;
typedef __attribute__((ext_vector_type(4))) unsigned short u16x4;
typedef __attribute__((ext_vector_type(2))) unsigned short u16x2;
typedef unsigned short u16;

#define NPIX 4096
#define CCH  512
#define DD   64

// All intermediate bf16 buffers are XOR-swizzled: within each 64-element
// k-group of row r, the 16B chunk at physical position p holds logical chunk
// p ^ (r&7). Linear global_load_lds staging then gives conflict-free b128
// fragment reads.
// k4 history: R8 8-phase NULL; R9 split-K (78.5 µs, best); R10-13: B-bypass /
// BM=256 variants all 81-91 µs. E-traffic halving NULL; schedule micro-
// structure NULL. Floors: MFMA 27, HBM 29, LDS 34, L2 ~25 µs -> 78.5 is
// imperfect-overlap-limited; deep-pipeline grafts failed twice. DECISION:
// k4 reverted to the exact measured-best R9 kernel; stop re-scheduling it.
// Round-14 (this): k3 epilogue vectorized via MFMA operand swap -- af=Q,
// bfr=K transposes the C-fragment so each lane's 4 accs are n-consecutive
// for fixed m -> one ds_write_b64 per (i,j) (16 b64) replaces 64 scalar
// ds_write_b16. Z-reduce becomes 4-step shfl_xor over l16. Tile layout,
// swizzle, and out-store loop unchanged.

__device__ inline float b2f(u16 h){
  union { unsigned int i; float f; } u; u.i = ((unsigned int)h) << 16; return u.f;
}
__device__ inline u16 f2b(float f){
  union { float f; unsigned int i; } u; u.f = f;
  return (u16)((u.i + 0x7fffu + ((u.i >> 16) & 1u)) >> 16);   // RNE
}
__device__ inline void gl2lds16(const void* g, void* l){
  __builtin_amdgcn_global_load_lds((const __attribute__((address_space(1))) unsigned int*)g,
                                   (__attribute__((address_space(3))) unsigned int*)l, 16, 0, 0);
}
__device__ inline f32x4 mfma16(short8 a, short8 b, f32x4 c){
  return __builtin_amdgcn_mfma_f32_16x16x32_bf16(a, b, c, 0, 0, 0);
}

// ---------------- k0: x fp32 (B,C,N) -> xT bf16 (B,N,C), swizzled.
// z==4 slice additionally converts Wq|Wk and Wv to swizzled bf16.
__global__ __launch_bounds__(256) void k0_transpose(const float* __restrict__ x,
    u16* __restrict__ xT, const float* __restrict__ Wq, const float* __restrict__ Wk,
    const float* __restrict__ Wv, u16* __restrict__ Wqkb, u16* __restrict__ Wvb){
  if (blockIdx.z == 4){
    // weight cvt: 512 blocks cover 65536 (Wqk) + 262144 (Wv) elements
    int bid = blockIdx.x * 8 + blockIdx.y;       // 0..511
    for (int r = 0; r < 3; ++r){
      int i = (r * 512 + bid) * 256 + threadIdx.x;   // 0..393215
      if (i < 65536){
        int row = i >> 9, col = i & 511;
        float v = (row < 64) ? Wq[(row << 9) + col] : Wk[((row - 64) << 9) + col];
        Wqkb[(row << 9) + (col ^ ((row & 7) << 3))] = f2b(v);
      } else if (i < 327680){
        int j = i - 65536;
        int row = j >> 9, col = j & 511;
        Wvb[(row << 9) + (col ^ ((row & 7) << 3))] = f2b(Wv[j]);
      }
    }
    return;
  }
  __shared__ u16 tile[64][66];   // [nn][cc]
  const int b = blockIdx.z;
  const int n0 = blockIdx.x * 64, c0 = blockIdx.y * 64;
  const float* xb = x + ((size_t)b * CCH + c0) * NPIX + n0;
  #pragma unroll
  for (int r = 0; r < 16; ++r){
    int id = r * 256 + threadIdx.x;
    int cc = id >> 6, nn = id & 63;
    tile[nn][cc] = f2b(xb[(size_t)cc * NPIX + nn]);
  }
  __syncthreads();
  u16* xTb = xT + ((size_t)b * NPIX + n0) * CCH + c0;
  #pragma unroll
  for (int r = 0; r < 8; ++r){
    int id = r * 256 + threadIdx.x;   // 0..2047
    int nn = id >> 5, c2 = id & 31;
    int colp = (2 * c2) ^ ((nn & 7) << 3);   // swizzle, keeps 4B alignment
    *(u16x2*)(xTb + (size_t)nn * CCH + colp) = *(const u16x2*)&tile[nn][2 * c2];
  }
}

// ---------------- k1: Q|K projection. rows=n, cols=128, K=512, BK=64 --------
__global__ __launch_bounds__(256) void k1_qk(const u16* __restrict__ xT,
    const u16* __restrict__ Wqk, const float* __restrict__ bq,
    const float* __restrict__ bk, u16* __restrict__ Qb, u16* __restrict__ Kb){
  __shared__ __align__(16) u16 As[128*64];
  __shared__ __align__(16) u16 Bs[128*64];
  const int b  = blockIdx.z;
  const int n0 = blockIdx.x * 128;
  const u16* Ab = xT + ((size_t)b * NPIX + n0) * CCH;
  const int t = threadIdx.x, wave = t >> 6, lane = t & 63, q = lane >> 4, l16 = lane & 15;
  const int wr = (wave >> 1) * 64, wc = (wave & 1) * 64;
  const int sw = l16 & 7;
  f32x4 acc[4][4];
  #pragma unroll
  for (int i = 0; i < 4; ++i)
    #pragma unroll
    for (int j = 0; j < 4; ++j) acc[i][j] = (f32x4){0.f,0.f,0.f,0.f};

  for (int k0 = 0; k0 < CCH; k0 += 64){
    __syncthreads();
    #pragma unroll
    for (int r = 0; r < 4; ++r){
      int id = r * 256 + t;           // 0..1023
      int row = id >> 3, ko = (id & 7) << 3;
      gl2lds16(Ab + (size_t)row * CCH + k0 + ko, &As[id * 8]);
      gl2lds16(Wqk + (size_t)row * CCH + k0 + ko, &Bs[id * 8]);
    }
    __syncthreads();
    #pragma unroll
    for (int s = 0; s < 2; ++s){
      const int ca = ((s*4 + q) ^ sw) << 3;
      short8 af[4], bfr[4];
      #pragma unroll
      for (int i = 0; i < 4; ++i){
        af[i]  = *(const short8*)&As[(wr + i*16 + l16)*64 + ca];
        bfr[i] = *(const short8*)&Bs[(wc + i*16 + l16)*64 + ca];
      }
      #pragma unroll
      for (int i = 0; i < 4; ++i)
        #pragma unroll
        for (int j = 0; j < 4; ++j)
          acc[i][j] = mfma16(af[i], bfr[j], acc[i][j]);
    }
  }
  #pragma unroll
  for (int i = 0; i < 4; ++i){
    #pragma unroll
    for (int j = 0; j < 4; ++j){
      int col = wc + j*16 + l16;
      #pragma unroll
      for (int r2 = 0; r2 < 4; ++r2){
        int n = n0 + wr + i*16 + q*4 + r2;
        int sw8 = (n & 7) << 3;
        float v = acc[i][j][r2];
        if (col < 64) Qb[((size_t)b * NPIX + n) * DD + (col ^ sw8)]        = f2b(v + bq[col]);
        else          Kb[((size_t)b * NPIX + n) * DD + ((col - 64) ^ sw8)] = f2b(v + bk[col - 64]);
      }
    }
  }
}

// ---------------- k2: V projection. rows=o (512), cols=n (4096), K=512, BK=64
__global__ __launch_bounds__(256) void k2_v(const u16* __restrict__ xT,
    const u16* __restrict__ Wvb, const float* __restrict__ bv, u16* __restrict__ Vb){
  __shared__ __align__(16) u16 As[128*64];
  __shared__ __align__(16) u16 Bs[128*64];
  const int b  = blockIdx.z;
  const int n0 = blockIdx.x * 128;
  const int o0 = blockIdx.y * 128;
  const u16* Ab = Wvb + (size_t)o0 * CCH;
  const u16* Bb = xT + ((size_t)b * NPIX + n0) * CCH;
  const int t = threadIdx.x, wave = t >> 6, lane = t & 63, q = lane >> 4, l16 = lane & 15;
  const int wr = (wave >> 1) * 64, wc = (wave & 1) * 64;
  const int sw = l16 & 7;
  f32x4 acc[4][4];
  #pragma unroll
  for (int i = 0; i < 4; ++i)
    #pragma unroll
    for (int j = 0; j < 4; ++j) acc[i][j] = (f32x4){0.f,0.f,0.f,0.f};

  for (int k0 = 0; k0 < CCH; k0 += 64){
    __syncthreads();
    #pragma unroll
    for (int r = 0; r < 4; ++r){
      int id = r * 256 + t;
      int row = id >> 3, ko = (id & 7) << 3;
      gl2lds16(Ab + (size_t)row * CCH + k0 + ko, &As[id * 8]);
      gl2lds16(Bb + (size_t)row * CCH + k0 + ko, &Bs[id * 8]);
    }
    __syncthreads();
    #pragma unroll
    for (int s = 0; s < 2; ++s){
      const int ca = ((s*4 + q) ^ sw) << 3;
      short8 af[4], bfr[4];
      #pragma unroll
      for (int i = 0; i < 4; ++i){
        af[i]  = *(const short8*)&As[(wr + i*16 + l16)*64 + ca];
        bfr[i] = *(const short8*)&Bs[(wc + i*16 + l16)*64 + ca];
      }
      #pragma unroll
      for (int i = 0; i < 4; ++i)
        #pragma unroll
        for (int j = 0; j < 4; ++j)
          acc[i][j] = mfma16(af[i], bfr[j], acc[i][j]);
    }
  }
  #pragma unroll
  for (int i = 0; i < 4; ++i){
    #pragma unroll
    for (int j = 0; j < 4; ++j){
      int n = n0 + wc + j*16 + l16;
      #pragma unroll
      for (int r2 = 0; r2 < 4; ++r2){
        int o = o0 + wr + i*16 + q*4 + r2;
        int np = n ^ ((o & 7) << 3);
        Vb[((size_t)b * CCH + o) * NPIX + np] = f2b(acc[i][j][r2] + bv[o]);
      }
    }
  }
}

// ---------------- k3: E[m][n]=exp(clamp(q_n.k_m)) swizzled; Z[n] += colsums -
// Round-14: MFMA operands swapped (af=Q rows n, bfr=K rows m) so the C
// fragment is [n-rows x m-cols]: each lane's 4 accs are n-consecutive for a
// fixed m -> packed 8B ds_write_b64 into the same [m][136] tile (16 writes
// vs 64 scalar). Z-reduce: per-(i,r2) shfl_xor over l16, atomic from l16==0.
__global__ __launch_bounds__(256) void k3_logits(const u16* __restrict__ Qb,
    const u16* __restrict__ Kb, u16* __restrict__ E, float* __restrict__ Z, int b0){
  __shared__ __align__(16) u16 smem[128*136];   // staging (32KB) then repack tile
  u16* As = smem;                // K rows m
  u16* Bs = smem + 128*64;       // Q rows n
  const int bloc = blockIdx.z, b = b0 + bloc;
  const int n0 = blockIdx.x * 128;
  const int m0 = blockIdx.y * 128;
  const u16* Ab = Kb + ((size_t)b * NPIX + m0) * DD;  // rows m
  const u16* Bb = Qb + ((size_t)b * NPIX + n0) * DD;  // cols n
  const int t = threadIdx.x, wave = t >> 6, lane = t & 63, q = lane >> 4, l16 = lane & 15;
  const int wr = (wave >> 1) * 64, wc = (wave & 1) * 64;  // wr: n-half, wc: m-half
  const int sw = l16 & 7;
  f32x4 acc[4][4];
  #pragma unroll
  for (int i = 0; i < 4; ++i)
    #pragma unroll
    for (int j = 0; j < 4; ++j) acc[i][j] = (f32x4){0.f,0.f,0.f,0.f};

  #pragma unroll
  for (int r = 0; r < 4; ++r){
    int id = r * 256 + t;
    int row = id >> 3, ko = (id & 7) << 3;
    gl2lds16(Ab + row * DD + ko, &As[id * 8]);
    gl2lds16(Bb + row * DD + ko, &Bs[id * 8]);
  }
  __syncthreads();
  #pragma unroll
  for (int s = 0; s < 2; ++s){
    const int ca = ((s*4 + q) ^ sw) << 3;
    short8 af[4], bfr[4];
    #pragma unroll
    for (int i = 0; i < 4; ++i){
      af[i]  = *(const short8*)&Bs[(wr + i*16 + l16)*64 + ca];   // Q (n)
      bfr[i] = *(const short8*)&As[(wc + i*16 + l16)*64 + ca];   // K (m)
    }
    #pragma unroll
    for (int i = 0; i < 4; ++i)
      #pragma unroll
      for (int j = 0; j < 4; ++j)
        acc[i][j] = mfma16(af[i], bfr[j], acc[i][j]);
  }
  // acc[i][j][r2]: n = n0 + wr + i*16 + q*4 + r2 ; m = m0 + wc + j*16 + l16
  __syncthreads();               // all waves done reading As/Bs; reuse smem
  u16* tile = smem;              // [128 m][136 n]
  float zp[4][4];
  #pragma unroll
  for (int i = 0; i < 4; ++i)
    #pragma unroll
    for (int r2 = 0; r2 < 4; ++r2) zp[i][r2] = 0.f;
  #pragma unroll
  for (int i = 0; i < 4; ++i){
    #pragma unroll
    for (int j = 0; j < 4; ++j){
      u16x4 pk;
      #pragma unroll
      for (int r2 = 0; r2 < 4; ++r2){
        // NaN firewall: legit logits are |l| <~ 12; clamp is semantically free
        float l = fminf(fmaxf(acc[i][j][r2], -60.f), 30.f);
        float e = __expf(l);
        pk[r2] = f2b(e);
        zp[i][r2] += e;
      }
      int mrow = wc + j*16 + l16;
      *(u16x4*)&tile[mrow * 136 + wr + i*16 + q*4] = pk;   // 8B packed write
    }
  }
  #pragma unroll
  for (int i = 0; i < 4; ++i){
    #pragma unroll
    for (int r2 = 0; r2 < 4; ++r2){
      float v = zp[i][r2];
      v += __shfl_xor(v, 1, 64);
      v += __shfl_xor(v, 2, 64);
      v += __shfl_xor(v, 4, 64);
      v += __shfl_xor(v, 8, 64);
      if (l16 == 0)
        atomicAdd(&Z[(size_t)b * NPIX + n0 + wr + i*16 + q*4 + r2], v);
    }
  }
  __syncthreads();
  u16* Eb = E + (size_t)bloc * NPIX * NPIX;
  #pragma unroll
  for (int r = 0; r < 8; ++r){
    int id = r * 256 + t;          // 0..2047
    int row = id >> 4, chunk = id & 15;
    int g = chunk >> 3, c3 = chunk & 7;
    int colp = g * 64 + ((c3 ^ (row & 7)) << 3);   // swizzled store
    *(u16x8*)(Eb + (size_t)(m0 + row) * NPIX + n0 + colp) =
        *(const u16x8*)&tile[row * 136 + chunk * 8];
  }
}

// ---------------- k3b: Vb = gamma * Vb / Z[n_logical]  (in place) -----------
__global__ __launch_bounds__(256) void k3b_scale(u16* __restrict__ Vb,
    const float* __restrict__ Z, const float* __restrict__ gm, int b0){
  size_t i4  = ((size_t)blockIdx.x * 256 + threadIdx.x) * 4;
  size_t off = ((size_t)b0 << 21) + i4;         // C*N = 2^21 per batch
  int b = (int)(off >> 21);
  int o = (int)((off >> 12) & 511);
  int np = (int)(off & (NPIX - 1));
  int nl = np ^ ((o & 7) << 3);                 // un-swizzle for Z lookup
  float g = gm[0];
  u16x4 vv = *(const u16x4*)(Vb + off);
  f32x4 zz = *(const f32x4*)(Z + ((size_t)b << 12) + nl);
  u16x4 r;
  #pragma unroll
  for (int k = 0; k < 4; ++k) r[k] = f2b(g * b2f(vv[k]) / fmaxf(zz[k], 1e-20f));
  *(u16x4*)(Vb + off) = r;
}

// ---------------- k4: out[o][m] = sum_n Vb'[o][n]*E[m][n] + x ---------------
// EXACT revert to the measured-best round-9 kernel (78.5 µs):
// BM=128(o) x BN=256(m) x BK=64(n), 512 thr / 8 waves. Wave tile 128x64
// (8x4 frags) via split-K-in-tile: wave group g = wave>>2 computes k-sub
// [32g,32g+32); 12 ds_read_b128 feed 32 MFMA. Triple-buffered LDS (144KB),
// 1 barrier + vmcnt(6) per K-tile. Epilogue: LDS reduction of the 2 halves.
__global__ __launch_bounds__(512, 2) void k4_out(const u16* __restrict__ Vs,
    const u16* __restrict__ E, const float* __restrict__ xin,
    float* __restrict__ outp, int b0){
  __shared__ __align__(16) u16 smem[3*128*64 + 3*256*64];   // 144KB
  u16* As = smem;                 // 3 x [128][64]
  u16* Bs = smem + 3*128*64;      // 3 x [256][64]
  const int bloc = blockIdx.z, b = b0 + bloc;
  const int m0 = blockIdx.x * 256;   // cols (E rows)
  const int o0 = blockIdx.y * 128;   // rows (V rows)
  const u16* Ab = Vs + ((size_t)b * CCH + o0) * NPIX;
  const u16* Bb = E + (size_t)bloc * NPIX * NPIX + (size_t)m0 * NPIX;
  const int t = threadIdx.x, wave = t >> 6, lane = t & 63, q = lane >> 4, l16 = lane & 15;
  const int grp = wave >> 2;         // k-slice group: 0 -> k[0,32), 1 -> k[32,64)
  const int br  = (wave & 3) * 64;   // wave m-range within block tile
  const int sw = l16 & 7;
  const int ca = ((grp * 4 + q) ^ sw) << 3;

  // per K-tile: A = 2 gl2lds/thread, B = 4 gl2lds/thread (6 total per wave)
  auto stageA = [&](int kt, int bi){
    const int k0 = kt << 6;
    u16* dst = As + bi * (128*64);
    #pragma unroll
    for (int r = 0; r < 2; ++r){
      int id = r * 512 + t;          // 0..1023: row=id>>3 (0..127)
      gl2lds16(Ab + (size_t)(id >> 3) * NPIX + (k0 + ((id & 7) << 3)), dst + id * 8);
    }
  };
  auto stageB = [&](int kt, int bi){
    const int k0 = kt << 6;
    u16* dst = Bs + bi * (256*64);
    #pragma unroll
    for (int r = 0; r < 4; ++r){
      int id = r * 512 + t;          // 0..2047: row=id>>3 (0..255)
      gl2lds16(Bb + (size_t)(id >> 3) * NPIX + (k0 + ((id & 7) << 3)), dst + id * 8);
    }
  };

  f32x4 acc[8][4];
  #pragma unroll
  for (int i = 0; i < 8; ++i)
    #pragma unroll
    for (int j = 0; j < 4; ++j) acc[i][j] = (f32x4){0.f,0.f,0.f,0.f};

  // prologue: tiles 0 and 1 in flight; wait for tile 0 (newest 6 = tile 1)
  stageA(0, 0); stageB(0, 0);
  stageA(1, 1); stageB(1, 1);
  asm volatile("s_waitcnt vmcnt(6)" ::: "memory");
  __builtin_amdgcn_sched_barrier(0);
  __builtin_amdgcn_s_barrier();

  int bi = 0;
  for (int kt = 0; kt < NPIX / 64; ++kt){
    const int bi2 = (bi >= 1) ? bi - 1 : 2;      // (bi+2)%3
    const bool pf = (kt + 2) < NPIX / 64;
    const u16* Ap = As + bi * (128*64);
    const u16* Bp = Bs + bi * (256*64);
    short8 af[8], bfr[4];
    #pragma unroll
    for (int i = 0; i < 8; ++i) af[i]  = *(const short8*)&Ap[(i*16 + l16)*64 + ca];
    #pragma unroll
    for (int j = 0; j < 4; ++j) bfr[j] = *(const short8*)&Bp[(br + j*16 + l16)*64 + ca];
    if (pf){ stageA(kt + 2, bi2); stageB(kt + 2, bi2); }
    asm volatile("s_waitcnt lgkmcnt(0)" ::: "memory");
    __builtin_amdgcn_sched_barrier(0);
    __builtin_amdgcn_s_setprio(1);
    #pragma unroll
    for (int i = 0; i < 8; ++i)
      #pragma unroll
      for (int j = 0; j < 4; ++j)
        acc[i][j] = mfma16(af[i], bfr[j], acc[i][j]);
    __builtin_amdgcn_s_setprio(0);
    // tile kt+1 must have fully landed before any wave reads it next iter;
    // only tile kt+2's 6 loads are allowed to stay in flight
    if (pf){ asm volatile("s_waitcnt vmcnt(6)" ::: "memory"); }
    else   { asm volatile("s_waitcnt vmcnt(0)" ::: "memory"); }
    __builtin_amdgcn_sched_barrier(0);
    __builtin_amdgcn_s_barrier();
    bi = (bi == 2) ? 0 : bi + 1;
  }

  // epilogue: merge the two k-halves. grp1 writes partials to LDS (buffers
  // are dead after the final barrier), grp0 adds + stores with residual.
  float* red = (float*)smem;       // [256][132] padded f32 = 132KB <= 144KB
  if (grp == 1){
    #pragma unroll
    for (int i = 0; i < 8; ++i)
      #pragma unroll
      for (int j = 0; j < 4; ++j)
        *(f32x4*)&red[(size_t)(br + j*16 + l16) * 132 + i*16 + q*4] = acc[i][j];
  }
  __syncthreads();
  if (grp == 0){
    const float* xb = xin + (size_t)b * CCH * NPIX;
    float* ob = outp + (size_t)b * CCH * NPIX;
    #pragma unroll
    for (int i = 0; i < 8; ++i){
      #pragma unroll
      for (int j = 0; j < 4; ++j){
        f32x4 p = *(const f32x4*)&red[(size_t)(br + j*16 + l16) * 132 + i*16 + q*4];
        int m = m0 + br + j*16 + l16;
        #pragma unroll
        for (int r2 = 0; r2 < 4; ++r2){
          int o = o0 + i*16 + q*4 + r2;
          size_t idx = (size_t)o * NPIX + m;
          ob[idx] = acc[i][j][r2] + p[r2] + xb[idx];
        }
      }
    }
  }
}

extern "C" void kernel_launch(void* const* d_in, const int* in_sizes, int n_in,
                              void* d_out, int out_size, void* d_ws, size_t ws_size,
                              hipStream_t stream){
  (void)in_sizes; (void)n_in; (void)out_size;
  const float* x  = (const float*)d_in[0];
  const float* Wq = (const float*)d_in[1];
  const float* bq = (const float*)d_in[2];
  const float* Wk = (const float*)d_in[3];
  const float* bk = (const float*)d_in[4];
  const float* Wv = (const float*)d_in[5];
  const float* bv = (const float*)d_in[6];
  const float* gm = (const float*)d_in[7];
  float* outp = (float*)d_out;

  // Workspace layout (E aliases xT: xT dead after k2):
  char* ws = (char*)d_ws;
  u16*  Qb   = (u16*)(ws + 0);
  u16*  Kb   = (u16*)(ws + 2097152);
  u16*  Vb   = (u16*)(ws + 4194304);
  float* Z   = (float*)(ws + 20971520);
  u16*  Wqkb = (u16*)(ws + 21037056);
  u16*  Wvb  = (u16*)(ws + 21168128);
  u16*  xT   = (u16*)(ws + 21692416);
  u16*  E    = (u16*)(ws + 21692416);

  const size_t ebytes = (size_t)NPIX * NPIX * 2;   // 33,554,432
  const size_t base   = 21692416;
  if (ws_size < base + ebytes){
    // DIAGNOSTIC: ws too small. Harness-zeroed output -> absmax == 5.4375
    return;
  }
  int NB = 1;
  if (ws_size >= base + 4 * ebytes) NB = 4;        // >= 155.9 MB
  else if (ws_size >= base + 2 * ebytes) NB = 2;   // >=  88.8 MB

  hipMemsetAsync(Z, 0, (size_t)4 * NPIX * sizeof(float), stream);
  // z slices 0..3: transpose; z slice 4: weight conversion
  k0_transpose<<<dim3(64, 8, 5), 256, 0, stream>>>(x, xT, Wq, Wk, Wv, Wqkb, Wvb);
  k1_qk<<<dim3(32, 1, 4), 256, 0, stream>>>(xT, Wqkb, bq, bk, Qb, Kb);
  k2_v<<<dim3(32, 4, 4), 256, 0, stream>>>(xT, Wvb, bv, Vb);
  for (int b0 = 0; b0 < 4; b0 += NB){
    int nb = NB; if (b0 + nb > 4) nb = 4 - b0;
    k3_logits<<<dim3(32, 32, nb), 256, 0, stream>>>(Qb, Kb, E, Z, b0);
    k3b_scale<<<dim3(nb * 2048), 256, 0, stream>>>(Vb, Z, gm, b0);
    k4_out<<<dim3(16, 4, nb), 512, 0, stream>>>(Vb, E, x, outp, b0);
  }
}

// Round 8
// 230.440 us; speedup vs baseline: 1.1311x; 1.1311x over previous
//
#include <hip/hip_runtime.h>
#include <stdint.h>

typedef __attribute__((ext_vector_type(8))) short short8;
typedef __attribute__((ext_vector_type(4))) float f32x4;
typedef __attribute__((ext_vector_type(8))) unsigned short u16x8;
typedef __attribute__((ext_vector_type(4))) unsigned short u16x4;
typedef __attribute__((ext_vector_type(2))) unsigned short u16x2;
typedef unsigned short u16;

#define NPIX 4096
#define CCH  512
#define DD   64

// All intermediate bf16 buffers are XOR-swizzled: within each 64-element
// k-group of row r, the 16B chunk at physical position p holds logical chunk
// p ^ (r&7). Linear global_load_lds staging then gives conflict-free b128
// fragment reads.
// k4 verdict (R8-R13): split-K R9 structure is the measured best (78.5 /
// 75.7 µs across two runs); 8-phase, B-bypass, BM=256, 2-blk variants all
// 81-91. Schedule micro-structure beyond split-K is NULL; k4 frozen.
// k3 verdict (R14): operand-swap + packed b64 writes REGRESSED ~25 µs
// (traded 48 LDS writes for 56 DS-pipe shuffles + 4x narrower atomics).
// Reverted to the R0 k3 that every good total was measured with.
// Cross-round totals carry +-8-15 µs noise (R0 vs R2 non-k4 identical code,
// 138 vs 156 µs) -- only same-round per-dispatch counters are trustworthy.

__device__ inline float b2f(u16 h){
  union { unsigned int i; float f; } u; u.i = ((unsigned int)h) << 16; return u.f;
}
__device__ inline u16 f2b(float f){
  union { float f; unsigned int i; } u; u.f = f;
  return (u16)((u.i + 0x7fffu + ((u.i >> 16) & 1u)) >> 16);   // RNE
}
__device__ inline void gl2lds16(const void* g, void* l){
  __builtin_amdgcn_global_load_lds((const __attribute__((address_space(1))) unsigned int*)g,
                                   (__attribute__((address_space(3))) unsigned int*)l, 16, 0, 0);
}
__device__ inline f32x4 mfma16(short8 a, short8 b, f32x4 c){
  return __builtin_amdgcn_mfma_f32_16x16x32_bf16(a, b, c, 0, 0, 0);
}

// ---------------- k0: x fp32 (B,C,N) -> xT bf16 (B,N,C), swizzled.
// z==4 slice additionally converts Wq|Wk and Wv to swizzled bf16.
__global__ __launch_bounds__(256) void k0_transpose(const float* __restrict__ x,
    u16* __restrict__ xT, const float* __restrict__ Wq, const float* __restrict__ Wk,
    const float* __restrict__ Wv, u16* __restrict__ Wqkb, u16* __restrict__ Wvb){
  if (blockIdx.z == 4){
    // weight cvt: 512 blocks cover 65536 (Wqk) + 262144 (Wv) elements
    int bid = blockIdx.x * 8 + blockIdx.y;       // 0..511
    for (int r = 0; r < 3; ++r){
      int i = (r * 512 + bid) * 256 + threadIdx.x;   // 0..393215
      if (i < 65536){
        int row = i >> 9, col = i & 511;
        float v = (row < 64) ? Wq[(row << 9) + col] : Wk[((row - 64) << 9) + col];
        Wqkb[(row << 9) + (col ^ ((row & 7) << 3))] = f2b(v);
      } else if (i < 327680){
        int j = i - 65536;
        int row = j >> 9, col = j & 511;
        Wvb[(row << 9) + (col ^ ((row & 7) << 3))] = f2b(Wv[j]);
      }
    }
    return;
  }
  __shared__ u16 tile[64][66];   // [nn][cc]
  const int b = blockIdx.z;
  const int n0 = blockIdx.x * 64, c0 = blockIdx.y * 64;
  const float* xb = x + ((size_t)b * CCH + c0) * NPIX + n0;
  #pragma unroll
  for (int r = 0; r < 16; ++r){
    int id = r * 256 + threadIdx.x;
    int cc = id >> 6, nn = id & 63;
    tile[nn][cc] = f2b(xb[(size_t)cc * NPIX + nn]);
  }
  __syncthreads();
  u16* xTb = xT + ((size_t)b * NPIX + n0) * CCH + c0;
  #pragma unroll
  for (int r = 0; r < 8; ++r){
    int id = r * 256 + threadIdx.x;   // 0..2047
    int nn = id >> 5, c2 = id & 31;
    int colp = (2 * c2) ^ ((nn & 7) << 3);   // swizzle, keeps 4B alignment
    *(u16x2*)(xTb + (size_t)nn * CCH + colp) = *(const u16x2*)&tile[nn][2 * c2];
  }
}

// ---------------- k1: Q|K projection. rows=n, cols=128, K=512, BK=64 --------
__global__ __launch_bounds__(256) void k1_qk(const u16* __restrict__ xT,
    const u16* __restrict__ Wqk, const float* __restrict__ bq,
    const float* __restrict__ bk, u16* __restrict__ Qb, u16* __restrict__ Kb){
  __shared__ __align__(16) u16 As[128*64];
  __shared__ __align__(16) u16 Bs[128*64];
  const int b  = blockIdx.z;
  const int n0 = blockIdx.x * 128;
  const u16* Ab = xT + ((size_t)b * NPIX + n0) * CCH;
  const int t = threadIdx.x, wave = t >> 6, lane = t & 63, q = lane >> 4, l16 = lane & 15;
  const int wr = (wave >> 1) * 64, wc = (wave & 1) * 64;
  const int sw = l16 & 7;
  f32x4 acc[4][4];
  #pragma unroll
  for (int i = 0; i < 4; ++i)
    #pragma unroll
    for (int j = 0; j < 4; ++j) acc[i][j] = (f32x4){0.f,0.f,0.f,0.f};

  for (int k0 = 0; k0 < CCH; k0 += 64){
    __syncthreads();
    #pragma unroll
    for (int r = 0; r < 4; ++r){
      int id = r * 256 + t;           // 0..1023
      int row = id >> 3, ko = (id & 7) << 3;
      gl2lds16(Ab + (size_t)row * CCH + k0 + ko, &As[id * 8]);
      gl2lds16(Wqk + (size_t)row * CCH + k0 + ko, &Bs[id * 8]);
    }
    __syncthreads();
    #pragma unroll
    for (int s = 0; s < 2; ++s){
      const int ca = ((s*4 + q) ^ sw) << 3;
      short8 af[4], bfr[4];
      #pragma unroll
      for (int i = 0; i < 4; ++i){
        af[i]  = *(const short8*)&As[(wr + i*16 + l16)*64 + ca];
        bfr[i] = *(const short8*)&Bs[(wc + i*16 + l16)*64 + ca];
      }
      #pragma unroll
      for (int i = 0; i < 4; ++i)
        #pragma unroll
        for (int j = 0; j < 4; ++j)
          acc[i][j] = mfma16(af[i], bfr[j], acc[i][j]);
    }
  }
  #pragma unroll
  for (int i = 0; i < 4; ++i){
    #pragma unroll
    for (int j = 0; j < 4; ++j){
      int col = wc + j*16 + l16;
      #pragma unroll
      for (int r2 = 0; r2 < 4; ++r2){
        int n = n0 + wr + i*16 + q*4 + r2;
        int sw8 = (n & 7) << 3;
        float v = acc[i][j][r2];
        if (col < 64) Qb[((size_t)b * NPIX + n) * DD + (col ^ sw8)]        = f2b(v + bq[col]);
        else          Kb[((size_t)b * NPIX + n) * DD + ((col - 64) ^ sw8)] = f2b(v + bk[col - 64]);
      }
    }
  }
}

// ---------------- k2: V projection. rows=o (512), cols=n (4096), K=512, BK=64
__global__ __launch_bounds__(256) void k2_v(const u16* __restrict__ xT,
    const u16* __restrict__ Wvb, const float* __restrict__ bv, u16* __restrict__ Vb){
  __shared__ __align__(16) u16 As[128*64];
  __shared__ __align__(16) u16 Bs[128*64];
  const int b  = blockIdx.z;
  const int n0 = blockIdx.x * 128;
  const int o0 = blockIdx.y * 128;
  const u16* Ab = Wvb + (size_t)o0 * CCH;
  const u16* Bb = xT + ((size_t)b * NPIX + n0) * CCH;
  const int t = threadIdx.x, wave = t >> 6, lane = t & 63, q = lane >> 4, l16 = lane & 15;
  const int wr = (wave >> 1) * 64, wc = (wave & 1) * 64;
  const int sw = l16 & 7;
  f32x4 acc[4][4];
  #pragma unroll
  for (int i = 0; i < 4; ++i)
    #pragma unroll
    for (int j = 0; j < 4; ++j) acc[i][j] = (f32x4){0.f,0.f,0.f,0.f};

  for (int k0 = 0; k0 < CCH; k0 += 64){
    __syncthreads();
    #pragma unroll
    for (int r = 0; r < 4; ++r){
      int id = r * 256 + t;
      int row = id >> 3, ko = (id & 7) << 3;
      gl2lds16(Ab + (size_t)row * CCH + k0 + ko, &As[id * 8]);
      gl2lds16(Bb + (size_t)row * CCH + k0 + ko, &Bs[id * 8]);
    }
    __syncthreads();
    #pragma unroll
    for (int s = 0; s < 2; ++s){
      const int ca = ((s*4 + q) ^ sw) << 3;
      short8 af[4], bfr[4];
      #pragma unroll
      for (int i = 0; i < 4; ++i){
        af[i]  = *(const short8*)&As[(wr + i*16 + l16)*64 + ca];
        bfr[i] = *(const short8*)&Bs[(wc + i*16 + l16)*64 + ca];
      }
      #pragma unroll
      for (int i = 0; i < 4; ++i)
        #pragma unroll
        for (int j = 0; j < 4; ++j)
          acc[i][j] = mfma16(af[i], bfr[j], acc[i][j]);
    }
  }
  #pragma unroll
  for (int i = 0; i < 4; ++i){
    #pragma unroll
    for (int j = 0; j < 4; ++j){
      int n = n0 + wc + j*16 + l16;
      #pragma unroll
      for (int r2 = 0; r2 < 4; ++r2){
        int o = o0 + wr + i*16 + q*4 + r2;
        int np = n ^ ((o & 7) << 3);
        Vb[((size_t)b * CCH + o) * NPIX + np] = f2b(acc[i][j][r2] + bv[o]);
      }
    }
  }
}

// ---------------- k3: E[m][n]=exp(clamp(q_n.k_m)) swizzled; Z[n] += colsums -
// (R0 version, restored: proven across every good total measurement.)
__global__ __launch_bounds__(256) void k3_logits(const u16* __restrict__ Qb,
    const u16* __restrict__ Kb, u16* __restrict__ E, float* __restrict__ Z, int b0){
  __shared__ __align__(16) u16 smem[128*136];   // staging (32KB) then repack tile
  u16* As = smem;
  u16* Bs = smem + 128*64;
  const int bloc = blockIdx.z, b = b0 + bloc;
  const int n0 = blockIdx.x * 128;
  const int m0 = blockIdx.y * 128;
  const u16* Ab = Kb + ((size_t)b * NPIX + m0) * DD;  // rows m
  const u16* Bb = Qb + ((size_t)b * NPIX + n0) * DD;  // cols n
  const int t = threadIdx.x, wave = t >> 6, lane = t & 63, q = lane >> 4, l16 = lane & 15;
  const int wr = (wave >> 1) * 64, wc = (wave & 1) * 64;
  const int sw = l16 & 7;
  f32x4 acc[4][4];
  #pragma unroll
  for (int i = 0; i < 4; ++i)
    #pragma unroll
    for (int j = 0; j < 4; ++j) acc[i][j] = (f32x4){0.f,0.f,0.f,0.f};

  #pragma unroll
  for (int r = 0; r < 4; ++r){
    int id = r * 256 + t;
    int row = id >> 3, ko = (id & 7) << 3;
    gl2lds16(Ab + row * DD + ko, &As[id * 8]);
    gl2lds16(Bb + row * DD + ko, &Bs[id * 8]);
  }
  __syncthreads();
  #pragma unroll
  for (int s = 0; s < 2; ++s){
    const int ca = ((s*4 + q) ^ sw) << 3;
    short8 af[4], bfr[4];
    #pragma unroll
    for (int i = 0; i < 4; ++i){
      af[i]  = *(const short8*)&As[(wr + i*16 + l16)*64 + ca];
      bfr[i] = *(const short8*)&Bs[(wc + i*16 + l16)*64 + ca];
    }
    #pragma unroll
    for (int i = 0; i < 4; ++i)
      #pragma unroll
      for (int j = 0; j < 4; ++j)
        acc[i][j] = mfma16(af[i], bfr[j], acc[i][j]);
  }
  __syncthreads();               // all waves done reading As/Bs; reuse smem
  u16* tile = smem;              // [128][136]
  float colsum[4] = {0.f, 0.f, 0.f, 0.f};
  #pragma unroll
  for (int i = 0; i < 4; ++i){
    #pragma unroll
    for (int j = 0; j < 4; ++j){
      #pragma unroll
      for (int r2 = 0; r2 < 4; ++r2){
        int mrow = wr + i*16 + q*4 + r2;
        int ncol = wc + j*16 + l16;
        // NaN firewall: legit logits are |l| <~ 12; clamp is semantically free
        float l = fminf(fmaxf(acc[i][j][r2], -60.f), 30.f);
        float e = __expf(l);
        tile[mrow * 136 + ncol] = f2b(e);
        colsum[j] += e;
      }
    }
  }
  #pragma unroll
  for (int j = 0; j < 4; ++j){
    float v = colsum[j];
    v += __shfl_xor(v, 16, 64);
    v += __shfl_xor(v, 32, 64);
    if (q == 0) atomicAdd(&Z[(size_t)b * NPIX + n0 + wc + j*16 + l16], v);
  }
  __syncthreads();
  u16* Eb = E + (size_t)bloc * NPIX * NPIX;
  #pragma unroll
  for (int r = 0; r < 8; ++r){
    int id = r * 256 + t;          // 0..2047
    int row = id >> 4, chunk = id & 15;
    int g = chunk >> 3, c3 = chunk & 7;
    int colp = g * 64 + ((c3 ^ (row & 7)) << 3);   // swizzled store
    *(u16x8*)(Eb + (size_t)(m0 + row) * NPIX + n0 + colp) =
        *(const u16x8*)&tile[row * 136 + chunk * 8];
  }
}

// ---------------- k3b: Vb = gamma * Vb / Z[n_logical]  (in place) -----------
__global__ __launch_bounds__(256) void k3b_scale(u16* __restrict__ Vb,
    const float* __restrict__ Z, const float* __restrict__ gm, int b0){
  size_t i4  = ((size_t)blockIdx.x * 256 + threadIdx.x) * 4;
  size_t off = ((size_t)b0 << 21) + i4;         // C*N = 2^21 per batch
  int b = (int)(off >> 21);
  int o = (int)((off >> 12) & 511);
  int np = (int)(off & (NPIX - 1));
  int nl = np ^ ((o & 7) << 3);                 // un-swizzle for Z lookup
  float g = gm[0];
  u16x4 vv = *(const u16x4*)(Vb + off);
  f32x4 zz = *(const f32x4*)(Z + ((size_t)b << 12) + nl);
  u16x4 r;
  #pragma unroll
  for (int k = 0; k < 4; ++k) r[k] = f2b(g * b2f(vv[k]) / fmaxf(zz[k], 1e-20f));
  *(u16x4*)(Vb + off) = r;
}

// ---------------- k4: out[o][m] = sum_n Vb'[o][n]*E[m][n] + x ---------------
// FROZEN: measured-best split-K structure (78.5 µs R9 / 75.7 µs R15):
// BM=128(o) x BN=256(m) x BK=64(n), 512 thr / 8 waves. Wave tile 128x64
// (8x4 frags) via split-K-in-tile: wave group g = wave>>2 computes k-sub
// [32g,32g+32); 12 ds_read_b128 feed 32 MFMA. Triple-buffered LDS (144KB),
// 1 barrier + vmcnt(6) per K-tile. Epilogue: LDS reduction of the 2 halves.
__global__ __launch_bounds__(512, 2) void k4_out(const u16* __restrict__ Vs,
    const u16* __restrict__ E, const float* __restrict__ xin,
    float* __restrict__ outp, int b0){
  __shared__ __align__(16) u16 smem[3*128*64 + 3*256*64];   // 144KB
  u16* As = smem;                 // 3 x [128][64]
  u16* Bs = smem + 3*128*64;      // 3 x [256][64]
  const int bloc = blockIdx.z, b = b0 + bloc;
  const int m0 = blockIdx.x * 256;   // cols (E rows)
  const int o0 = blockIdx.y * 128;   // rows (V rows)
  const u16* Ab = Vs + ((size_t)b * CCH + o0) * NPIX;
  const u16* Bb = E + (size_t)bloc * NPIX * NPIX + (size_t)m0 * NPIX;
  const int t = threadIdx.x, wave = t >> 6, lane = t & 63, q = lane >> 4, l16 = lane & 15;
  const int grp = wave >> 2;         // k-slice group: 0 -> k[0,32), 1 -> k[32,64)
  const int br  = (wave & 3) * 64;   // wave m-range within block tile
  const int sw = l16 & 7;
  const int ca = ((grp * 4 + q) ^ sw) << 3;

  // per K-tile: A = 2 gl2lds/thread, B = 4 gl2lds/thread (6 total per wave)
  auto stageA = [&](int kt, int bi){
    const int k0 = kt << 6;
    u16* dst = As + bi * (128*64);
    #pragma unroll
    for (int r = 0; r < 2; ++r){
      int id = r * 512 + t;          // 0..1023: row=id>>3 (0..127)
      gl2lds16(Ab + (size_t)(id >> 3) * NPIX + (k0 + ((id & 7) << 3)), dst + id * 8);
    }
  };
  auto stageB = [&](int kt, int bi){
    const int k0 = kt << 6;
    u16* dst = Bs + bi * (256*64);
    #pragma unroll
    for (int r = 0; r < 4; ++r){
      int id = r * 512 + t;          // 0..2047: row=id>>3 (0..255)
      gl2lds16(Bb + (size_t)(id >> 3) * NPIX + (k0 + ((id & 7) << 3)), dst + id * 8);
    }
  };

  f32x4 acc[8][4];
  #pragma unroll
  for (int i = 0; i < 8; ++i)
    #pragma unroll
    for (int j = 0; j < 4; ++j) acc[i][j] = (f32x4){0.f,0.f,0.f,0.f};

  // prologue: tiles 0 and 1 in flight; wait for tile 0 (newest 6 = tile 1)
  stageA(0, 0); stageB(0, 0);
  stageA(1, 1); stageB(1, 1);
  asm volatile("s_waitcnt vmcnt(6)" ::: "memory");
  __builtin_amdgcn_sched_barrier(0);
  __builtin_amdgcn_s_barrier();

  int bi = 0;
  for (int kt = 0; kt < NPIX / 64; ++kt){
    const int bi2 = (bi >= 1) ? bi - 1 : 2;      // (bi+2)%3
    const bool pf = (kt + 2) < NPIX / 64;
    const u16* Ap = As + bi * (128*64);
    const u16* Bp = Bs + bi * (256*64);
    short8 af[8], bfr[4];
    #pragma unroll
    for (int i = 0; i < 8; ++i) af[i]  = *(const short8*)&Ap[(i*16 + l16)*64 + ca];
    #pragma unroll
    for (int j = 0; j < 4; ++j) bfr[j] = *(const short8*)&Bp[(br + j*16 + l16)*64 + ca];
    if (pf){ stageA(kt + 2, bi2); stageB(kt + 2, bi2); }
    asm volatile("s_waitcnt lgkmcnt(0)" ::: "memory");
    __builtin_amdgcn_sched_barrier(0);
    __builtin_amdgcn_s_setprio(1);
    #pragma unroll
    for (int i = 0; i < 8; ++i)
      #pragma unroll
      for (int j = 0; j < 4; ++j)
        acc[i][j] = mfma16(af[i], bfr[j], acc[i][j]);
    __builtin_amdgcn_s_setprio(0);
    // tile kt+1 must have fully landed before any wave reads it next iter;
    // only tile kt+2's 6 loads are allowed to stay in flight
    if (pf){ asm volatile("s_waitcnt vmcnt(6)" ::: "memory"); }
    else   { asm volatile("s_waitcnt vmcnt(0)" ::: "memory"); }
    __builtin_amdgcn_sched_barrier(0);
    __builtin_amdgcn_s_barrier();
    bi = (bi == 2) ? 0 : bi + 1;
  }

  // epilogue: merge the two k-halves. grp1 writes partials to LDS (buffers
  // are dead after the final barrier), grp0 adds + stores with residual.
  float* red = (float*)smem;       // [256][132] padded f32 = 132KB <= 144KB
  if (grp == 1){
    #pragma unroll
    for (int i = 0; i < 8; ++i)
      #pragma unroll
      for (int j = 0; j < 4; ++j)
        *(f32x4*)&red[(size_t)(br + j*16 + l16) * 132 + i*16 + q*4] = acc[i][j];
  }
  __syncthreads();
  if (grp == 0){
    const float* xb = xin + (size_t)b * CCH * NPIX;
    float* ob = outp + (size_t)b * CCH * NPIX;
    #pragma unroll
    for (int i = 0; i < 8; ++i){
      #pragma unroll
      for (int j = 0; j < 4; ++j){
        f32x4 p = *(const f32x4*)&red[(size_t)(br + j*16 + l16) * 132 + i*16 + q*4];
        int m = m0 + br + j*16 + l16;
        #pragma unroll
        for (int r2 = 0; r2 < 4; ++r2){
          int o = o0 + i*16 + q*4 + r2;
          size_t idx = (size_t)o * NPIX + m;
          ob[idx] = acc[i][j][r2] + p[r2] + xb[idx];
        }
      }
    }
  }
}

extern "C" void kernel_launch(void* const* d_in, const int* in_sizes, int n_in,
                              void* d_out, int out_size, void* d_ws, size_t ws_size,
                              hipStream_t stream){
  (void)in_sizes; (void)n_in; (void)out_size;
  const float* x  = (const float*)d_in[0];
  const float* Wq = (const float*)d_in[1];
  const float* bq = (const float*)d_in[2];
  const float* Wk = (const float*)d_in[3];
  const float* bk = (const float*)d_in[4];
  const float* Wv = (const float*)d_in[5];
  const float* bv = (const float*)d_in[6];
  const float* gm = (const float*)d_in[7];
  float* outp = (float*)d_out;

  // Workspace layout (E aliases xT: xT dead after k2):
  char* ws = (char*)d_ws;
  u16*  Qb   = (u16*)(ws + 0);
  u16*  Kb   = (u16*)(ws + 2097152);
  u16*  Vb   = (u16*)(ws + 4194304);
  float* Z   = (float*)(ws + 20971520);
  u16*  Wqkb = (u16*)(ws + 21037056);
  u16*  Wvb  = (u16*)(ws + 21168128);
  u16*  xT   = (u16*)(ws + 21692416);
  u16*  E    = (u16*)(ws + 21692416);

  const size_t ebytes = (size_t)NPIX * NPIX * 2;   // 33,554,432
  const size_t base   = 21692416;
  if (ws_size < base + ebytes){
    // DIAGNOSTIC: ws too small. Harness-zeroed output -> absmax == 5.4375
    return;
  }
  int NB = 1;
  if (ws_size >= base + 4 * ebytes) NB = 4;        // >= 155.9 MB
  else if (ws_size >= base + 2 * ebytes) NB = 2;   // >=  88.8 MB

  hipMemsetAsync(Z, 0, (size_t)4 * NPIX * sizeof(float), stream);
  // z slices 0..3: transpose; z slice 4: weight conversion
  k0_transpose<<<dim3(64, 8, 5), 256, 0, stream>>>(x, xT, Wq, Wk, Wv, Wqkb, Wvb);
  k1_qk<<<dim3(32, 1, 4), 256, 0, stream>>>(xT, Wqkb, bq, bk, Qb, Kb);
  k2_v<<<dim3(32, 4, 4), 256, 0, stream>>>(xT, Wvb, bv, Vb);
  for (int b0 = 0; b0 < 4; b0 += NB){
    int nb = NB; if (b0 + nb > 4) nb = 4 - b0;
    k3_logits<<<dim3(32, 32, nb), 256, 0, stream>>>(Qb, Kb, E, Z, b0);
    k3b_scale<<<dim3(nb * 2048), 256, 0, stream>>>(Vb, Z, gm, b0);
    k4_out<<<dim3(16, 4, nb), 512, 0, stream>>>(Vb, E, x, outp, b0);
  }
}

// Round 9
// 228.015 us; speedup vs baseline: 1.1431x; 1.0106x over previous
//
#include <hip/hip_runtime.h>
#include <stdint.h>

typedef __attribute__((ext_vector_type(8))) short short8;
typedef __attribute__((ext_vector_type(4))) float f32x4;
typedef __attribute__((ext_vector_type(8))) unsigned short u16x8;
typedef __attribute__((ext_vector_type(4))) unsigned short u16x4;
typedef __attribute__((ext_vector_type(2))) unsigned short u16x2;
typedef unsigned short u16;

#define NPIX 4096
#define CCH  512
#define DD   64

// All intermediate bf16 buffers are XOR-swizzled: within each 64-element
// k-group of row r, the 16B chunk at physical position p holds logical chunk
// p ^ (r&7). Linear global_load_lds staging then gives conflict-free b128
// fragment reads.
// k4 verdict (R8-R15): split-K structure is the measured best (78.5 / 75.7 /
// 76.1 µs across three runs); all pipeline/tiling variants 81-91. FROZEN.
// k3 verdict (R14): operand-swap packed writes regressed; R0 k3 restored.
// Round-16 (this): k3b eliminated WHEN ws_size PERMITS -- placing E after xT
// (no alias, needs 172.7 MB) allows order k3 -> k2, so k2's epilogue applies
// gamma/Z to the fp32 accumulator directly (single rounding, one less pass).
// Fallback: exact old aliased path (k2 -> {k3,k3b,k4} per batch group).
// Cross-round totals carry +-8-15 µs noise; only per-dispatch counters are
// trustworthy below 10%.

__device__ inline float b2f(u16 h){
  union { unsigned int i; float f; } u; u.i = ((unsigned int)h) << 16; return u.f;
}
__device__ inline u16 f2b(float f){
  union { float f; unsigned int i; } u; u.f = f;
  return (u16)((u.i + 0x7fffu + ((u.i >> 16) & 1u)) >> 16);   // RNE
}
__device__ inline void gl2lds16(const void* g, void* l){
  __builtin_amdgcn_global_load_lds((const __attribute__((address_space(1))) unsigned int*)g,
                                   (__attribute__((address_space(3))) unsigned int*)l, 16, 0, 0);
}
__device__ inline f32x4 mfma16(short8 a, short8 b, f32x4 c){
  return __builtin_amdgcn_mfma_f32_16x16x32_bf16(a, b, c, 0, 0, 0);
}

// ---------------- k0: x fp32 (B,C,N) -> xT bf16 (B,N,C), swizzled.
// z==4 slice additionally converts Wq|Wk and Wv to swizzled bf16.
__global__ __launch_bounds__(256) void k0_transpose(const float* __restrict__ x,
    u16* __restrict__ xT, const float* __restrict__ Wq, const float* __restrict__ Wk,
    const float* __restrict__ Wv, u16* __restrict__ Wqkb, u16* __restrict__ Wvb){
  if (blockIdx.z == 4){
    // weight cvt: 512 blocks cover 65536 (Wqk) + 262144 (Wv) elements
    int bid = blockIdx.x * 8 + blockIdx.y;       // 0..511
    for (int r = 0; r < 3; ++r){
      int i = (r * 512 + bid) * 256 + threadIdx.x;   // 0..393215
      if (i < 65536){
        int row = i >> 9, col = i & 511;
        float v = (row < 64) ? Wq[(row << 9) + col] : Wk[((row - 64) << 9) + col];
        Wqkb[(row << 9) + (col ^ ((row & 7) << 3))] = f2b(v);
      } else if (i < 327680){
        int j = i - 65536;
        int row = j >> 9, col = j & 511;
        Wvb[(row << 9) + (col ^ ((row & 7) << 3))] = f2b(Wv[j]);
      }
    }
    return;
  }
  __shared__ u16 tile[64][66];   // [nn][cc]
  const int b = blockIdx.z;
  const int n0 = blockIdx.x * 64, c0 = blockIdx.y * 64;
  const float* xb = x + ((size_t)b * CCH + c0) * NPIX + n0;
  #pragma unroll
  for (int r = 0; r < 16; ++r){
    int id = r * 256 + threadIdx.x;
    int cc = id >> 6, nn = id & 63;
    tile[nn][cc] = f2b(xb[(size_t)cc * NPIX + nn]);
  }
  __syncthreads();
  u16* xTb = xT + ((size_t)b * NPIX + n0) * CCH + c0;
  #pragma unroll
  for (int r = 0; r < 8; ++r){
    int id = r * 256 + threadIdx.x;   // 0..2047
    int nn = id >> 5, c2 = id & 31;
    int colp = (2 * c2) ^ ((nn & 7) << 3);   // swizzle, keeps 4B alignment
    *(u16x2*)(xTb + (size_t)nn * CCH + colp) = *(const u16x2*)&tile[nn][2 * c2];
  }
}

// ---------------- k1: Q|K projection. rows=n, cols=128, K=512, BK=64 --------
__global__ __launch_bounds__(256) void k1_qk(const u16* __restrict__ xT,
    const u16* __restrict__ Wqk, const float* __restrict__ bq,
    const float* __restrict__ bk, u16* __restrict__ Qb, u16* __restrict__ Kb){
  __shared__ __align__(16) u16 As[128*64];
  __shared__ __align__(16) u16 Bs[128*64];
  const int b  = blockIdx.z;
  const int n0 = blockIdx.x * 128;
  const u16* Ab = xT + ((size_t)b * NPIX + n0) * CCH;
  const int t = threadIdx.x, wave = t >> 6, lane = t & 63, q = lane >> 4, l16 = lane & 15;
  const int wr = (wave >> 1) * 64, wc = (wave & 1) * 64;
  const int sw = l16 & 7;
  f32x4 acc[4][4];
  #pragma unroll
  for (int i = 0; i < 4; ++i)
    #pragma unroll
    for (int j = 0; j < 4; ++j) acc[i][j] = (f32x4){0.f,0.f,0.f,0.f};

  for (int k0 = 0; k0 < CCH; k0 += 64){
    __syncthreads();
    #pragma unroll
    for (int r = 0; r < 4; ++r){
      int id = r * 256 + t;           // 0..1023
      int row = id >> 3, ko = (id & 7) << 3;
      gl2lds16(Ab + (size_t)row * CCH + k0 + ko, &As[id * 8]);
      gl2lds16(Wqk + (size_t)row * CCH + k0 + ko, &Bs[id * 8]);
    }
    __syncthreads();
    #pragma unroll
    for (int s = 0; s < 2; ++s){
      const int ca = ((s*4 + q) ^ sw) << 3;
      short8 af[4], bfr[4];
      #pragma unroll
      for (int i = 0; i < 4; ++i){
        af[i]  = *(const short8*)&As[(wr + i*16 + l16)*64 + ca];
        bfr[i] = *(const short8*)&Bs[(wc + i*16 + l16)*64 + ca];
      }
      #pragma unroll
      for (int i = 0; i < 4; ++i)
        #pragma unroll
        for (int j = 0; j < 4; ++j)
          acc[i][j] = mfma16(af[i], bfr[j], acc[i][j]);
    }
  }
  #pragma unroll
  for (int i = 0; i < 4; ++i){
    #pragma unroll
    for (int j = 0; j < 4; ++j){
      int col = wc + j*16 + l16;
      #pragma unroll
      for (int r2 = 0; r2 < 4; ++r2){
        int n = n0 + wr + i*16 + q*4 + r2;
        int sw8 = (n & 7) << 3;
        float v = acc[i][j][r2];
        if (col < 64) Qb[((size_t)b * NPIX + n) * DD + (col ^ sw8)]        = f2b(v + bq[col]);
        else          Kb[((size_t)b * NPIX + n) * DD + ((col - 64) ^ sw8)] = f2b(v + bk[col - 64]);
      }
    }
  }
}

// ---------------- k2: V projection. rows=o (512), cols=n (4096), K=512, BK=64
// fused==1: epilogue applies V = gamma*(acc+bv)/max(Z[n],eps) (k3b folded in;
// requires Z complete, i.e. k3 launched before k2 in the no-alias path).
__global__ __launch_bounds__(256) void k2_v(const u16* __restrict__ xT,
    const u16* __restrict__ Wvb, const float* __restrict__ bv, u16* __restrict__ Vb,
    const float* __restrict__ Z, const float* __restrict__ gm, int fused){
  __shared__ __align__(16) u16 As[128*64];
  __shared__ __align__(16) u16 Bs[128*64];
  const int b  = blockIdx.z;
  const int n0 = blockIdx.x * 128;
  const int o0 = blockIdx.y * 128;
  const u16* Ab = Wvb + (size_t)o0 * CCH;
  const u16* Bb = xT + ((size_t)b * NPIX + n0) * CCH;
  const int t = threadIdx.x, wave = t >> 6, lane = t & 63, q = lane >> 4, l16 = lane & 15;
  const int wr = (wave >> 1) * 64, wc = (wave & 1) * 64;
  const int sw = l16 & 7;
  f32x4 acc[4][4];
  #pragma unroll
  for (int i = 0; i < 4; ++i)
    #pragma unroll
    for (int j = 0; j < 4; ++j) acc[i][j] = (f32x4){0.f,0.f,0.f,0.f};

  for (int k0 = 0; k0 < CCH; k0 += 64){
    __syncthreads();
    #pragma unroll
    for (int r = 0; r < 4; ++r){
      int id = r * 256 + t;
      int row = id >> 3, ko = (id & 7) << 3;
      gl2lds16(Ab + (size_t)row * CCH + k0 + ko, &As[id * 8]);
      gl2lds16(Bb + (size_t)row * CCH + k0 + ko, &Bs[id * 8]);
    }
    __syncthreads();
    #pragma unroll
    for (int s = 0; s < 2; ++s){
      const int ca = ((s*4 + q) ^ sw) << 3;
      short8 af[4], bfr[4];
      #pragma unroll
      for (int i = 0; i < 4; ++i){
        af[i]  = *(const short8*)&As[(wr + i*16 + l16)*64 + ca];
        bfr[i] = *(const short8*)&Bs[(wc + i*16 + l16)*64 + ca];
      }
      #pragma unroll
      for (int i = 0; i < 4; ++i)
        #pragma unroll
        for (int j = 0; j < 4; ++j)
          acc[i][j] = mfma16(af[i], bfr[j], acc[i][j]);
    }
  }
  float zs[4];
  #pragma unroll
  for (int j = 0; j < 4; ++j) zs[j] = 1.f;
  if (fused){
    float g = gm[0];
    #pragma unroll
    for (int j = 0; j < 4; ++j){
      int n = n0 + wc + j*16 + l16;
      zs[j] = g / fmaxf(Z[(size_t)b * NPIX + n], 1e-20f);
    }
  }
  #pragma unroll
  for (int i = 0; i < 4; ++i){
    #pragma unroll
    for (int j = 0; j < 4; ++j){
      int n = n0 + wc + j*16 + l16;
      #pragma unroll
      for (int r2 = 0; r2 < 4; ++r2){
        int o = o0 + wr + i*16 + q*4 + r2;
        int np = n ^ ((o & 7) << 3);
        float v = acc[i][j][r2] + bv[o];
        if (fused) v *= zs[j];
        Vb[((size_t)b * CCH + o) * NPIX + np] = f2b(v);
      }
    }
  }
}

// ---------------- k3: E[m][n]=exp(clamp(q_n.k_m)) swizzled; Z[n] += colsums -
// (R0 version: proven across every good total measurement.)
__global__ __launch_bounds__(256) void k3_logits(const u16* __restrict__ Qb,
    const u16* __restrict__ Kb, u16* __restrict__ E, float* __restrict__ Z, int b0){
  __shared__ __align__(16) u16 smem[128*136];   // staging (32KB) then repack tile
  u16* As = smem;
  u16* Bs = smem + 128*64;
  const int bloc = blockIdx.z, b = b0 + bloc;
  const int n0 = blockIdx.x * 128;
  const int m0 = blockIdx.y * 128;
  const u16* Ab = Kb + ((size_t)b * NPIX + m0) * DD;  // rows m
  const u16* Bb = Qb + ((size_t)b * NPIX + n0) * DD;  // cols n
  const int t = threadIdx.x, wave = t >> 6, lane = t & 63, q = lane >> 4, l16 = lane & 15;
  const int wr = (wave >> 1) * 64, wc = (wave & 1) * 64;
  const int sw = l16 & 7;
  f32x4 acc[4][4];
  #pragma unroll
  for (int i = 0; i < 4; ++i)
    #pragma unroll
    for (int j = 0; j < 4; ++j) acc[i][j] = (f32x4){0.f,0.f,0.f,0.f};

  #pragma unroll
  for (int r = 0; r < 4; ++r){
    int id = r * 256 + t;
    int row = id >> 3, ko = (id & 7) << 3;
    gl2lds16(Ab + row * DD + ko, &As[id * 8]);
    gl2lds16(Bb + row * DD + ko, &Bs[id * 8]);
  }
  __syncthreads();
  #pragma unroll
  for (int s = 0; s < 2; ++s){
    const int ca = ((s*4 + q) ^ sw) << 3;
    short8 af[4], bfr[4];
    #pragma unroll
    for (int i = 0; i < 4; ++i){
      af[i]  = *(const short8*)&As[(wr + i*16 + l16)*64 + ca];
      bfr[i] = *(const short8*)&Bs[(wc + i*16 + l16)*64 + ca];
    }
    #pragma unroll
    for (int i = 0; i < 4; ++i)
      #pragma unroll
      for (int j = 0; j < 4; ++j)
        acc[i][j] = mfma16(af[i], bfr[j], acc[i][j]);
  }
  __syncthreads();               // all waves done reading As/Bs; reuse smem
  u16* tile = smem;              // [128][136]
  float colsum[4] = {0.f, 0.f, 0.f, 0.f};
  #pragma unroll
  for (int i = 0; i < 4; ++i){
    #pragma unroll
    for (int j = 0; j < 4; ++j){
      #pragma unroll
      for (int r2 = 0; r2 < 4; ++r2){
        int mrow = wr + i*16 + q*4 + r2;
        int ncol = wc + j*16 + l16;
        // NaN firewall: legit logits are |l| <~ 12; clamp is semantically free
        float l = fminf(fmaxf(acc[i][j][r2], -60.f), 30.f);
        float e = __expf(l);
        tile[mrow * 136 + ncol] = f2b(e);
        colsum[j] += e;
      }
    }
  }
  #pragma unroll
  for (int j = 0; j < 4; ++j){
    float v = colsum[j];
    v += __shfl_xor(v, 16, 64);
    v += __shfl_xor(v, 32, 64);
    if (q == 0) atomicAdd(&Z[(size_t)b * NPIX + n0 + wc + j*16 + l16], v);
  }
  __syncthreads();
  u16* Eb = E + (size_t)bloc * NPIX * NPIX;
  #pragma unroll
  for (int r = 0; r < 8; ++r){
    int id = r * 256 + t;          // 0..2047
    int row = id >> 4, chunk = id & 15;
    int g = chunk >> 3, c3 = chunk & 7;
    int colp = g * 64 + ((c3 ^ (row & 7)) << 3);   // swizzled store
    *(u16x8*)(Eb + (size_t)(m0 + row) * NPIX + n0 + colp) =
        *(const u16x8*)&tile[row * 136 + chunk * 8];
  }
}

// ---------------- k3b: Vb = gamma * Vb / Z[n_logical]  (in place) -----------
// (only launched on the aliased fallback path)
__global__ __launch_bounds__(256) void k3b_scale(u16* __restrict__ Vb,
    const float* __restrict__ Z, const float* __restrict__ gm, int b0){
  size_t i4  = ((size_t)blockIdx.x * 256 + threadIdx.x) * 4;
  size_t off = ((size_t)b0 << 21) + i4;         // C*N = 2^21 per batch
  int b = (int)(off >> 21);
  int o = (int)((off >> 12) & 511);
  int np = (int)(off & (NPIX - 1));
  int nl = np ^ ((o & 7) << 3);                 // un-swizzle for Z lookup
  float g = gm[0];
  u16x4 vv = *(const u16x4*)(Vb + off);
  f32x4 zz = *(const f32x4*)(Z + ((size_t)b << 12) + nl);
  u16x4 r;
  #pragma unroll
  for (int k = 0; k < 4; ++k) r[k] = f2b(g * b2f(vv[k]) / fmaxf(zz[k], 1e-20f));
  *(u16x4*)(Vb + off) = r;
}

// ---------------- k4: out[o][m] = sum_n Vb'[o][n]*E[m][n] + x ---------------
// FROZEN: measured-best split-K structure (78.5/75.7/76.1 µs across 3 runs):
// BM=128(o) x BN=256(m) x BK=64(n), 512 thr / 8 waves. Wave tile 128x64
// (8x4 frags) via split-K-in-tile: wave group g = wave>>2 computes k-sub
// [32g,32g+32); 12 ds_read_b128 feed 32 MFMA. Triple-buffered LDS (144KB),
// 1 barrier + vmcnt(6) per K-tile. Epilogue: LDS reduction of the 2 halves.
__global__ __launch_bounds__(512, 2) void k4_out(const u16* __restrict__ Vs,
    const u16* __restrict__ E, const float* __restrict__ xin,
    float* __restrict__ outp, int b0){
  __shared__ __align__(16) u16 smem[3*128*64 + 3*256*64];   // 144KB
  u16* As = smem;                 // 3 x [128][64]
  u16* Bs = smem + 3*128*64;      // 3 x [256][64]
  const int bloc = blockIdx.z, b = b0 + bloc;
  const int m0 = blockIdx.x * 256;   // cols (E rows)
  const int o0 = blockIdx.y * 128;   // rows (V rows)
  const u16* Ab = Vs + ((size_t)b * CCH + o0) * NPIX;
  const u16* Bb = E + (size_t)bloc * NPIX * NPIX + (size_t)m0 * NPIX;
  const int t = threadIdx.x, wave = t >> 6, lane = t & 63, q = lane >> 4, l16 = lane & 15;
  const int grp = wave >> 2;         // k-slice group: 0 -> k[0,32), 1 -> k[32,64)
  const int br  = (wave & 3) * 64;   // wave m-range within block tile
  const int sw = l16 & 7;
  const int ca = ((grp * 4 + q) ^ sw) << 3;

  // per K-tile: A = 2 gl2lds/thread, B = 4 gl2lds/thread (6 total per wave)
  auto stageA = [&](int kt, int bi){
    const int k0 = kt << 6;
    u16* dst = As + bi * (128*64);
    #pragma unroll
    for (int r = 0; r < 2; ++r){
      int id = r * 512 + t;          // 0..1023: row=id>>3 (0..127)
      gl2lds16(Ab + (size_t)(id >> 3) * NPIX + (k0 + ((id & 7) << 3)), dst + id * 8);
    }
  };
  auto stageB = [&](int kt, int bi){
    const int k0 = kt << 6;
    u16* dst = Bs + bi * (256*64);
    #pragma unroll
    for (int r = 0; r < 4; ++r){
      int id = r * 512 + t;          // 0..2047: row=id>>3 (0..255)
      gl2lds16(Bb + (size_t)(id >> 3) * NPIX + (k0 + ((id & 7) << 3)), dst + id * 8);
    }
  };

  f32x4 acc[8][4];
  #pragma unroll
  for (int i = 0; i < 8; ++i)
    #pragma unroll
    for (int j = 0; j < 4; ++j) acc[i][j] = (f32x4){0.f,0.f,0.f,0.f};

  // prologue: tiles 0 and 1 in flight; wait for tile 0 (newest 6 = tile 1)
  stageA(0, 0); stageB(0, 0);
  stageA(1, 1); stageB(1, 1);
  asm volatile("s_waitcnt vmcnt(6)" ::: "memory");
  __builtin_amdgcn_sched_barrier(0);
  __builtin_amdgcn_s_barrier();

  int bi = 0;
  for (int kt = 0; kt < NPIX / 64; ++kt){
    const int bi2 = (bi >= 1) ? bi - 1 : 2;      // (bi+2)%3
    const bool pf = (kt + 2) < NPIX / 64;
    const u16* Ap = As + bi * (128*64);
    const u16* Bp = Bs + bi * (256*64);
    short8 af[8], bfr[4];
    #pragma unroll
    for (int i = 0; i < 8; ++i) af[i]  = *(const short8*)&Ap[(i*16 + l16)*64 + ca];
    #pragma unroll
    for (int j = 0; j < 4; ++j) bfr[j] = *(const short8*)&Bp[(br + j*16 + l16)*64 + ca];
    if (pf){ stageA(kt + 2, bi2); stageB(kt + 2, bi2); }
    asm volatile("s_waitcnt lgkmcnt(0)" ::: "memory");
    __builtin_amdgcn_sched_barrier(0);
    __builtin_amdgcn_s_setprio(1);
    #pragma unroll
    for (int i = 0; i < 8; ++i)
      #pragma unroll
      for (int j = 0; j < 4; ++j)
        acc[i][j] = mfma16(af[i], bfr[j], acc[i][j]);
    __builtin_amdgcn_s_setprio(0);
    // tile kt+1 must have fully landed before any wave reads it next iter;
    // only tile kt+2's 6 loads are allowed to stay in flight
    if (pf){ asm volatile("s_waitcnt vmcnt(6)" ::: "memory"); }
    else   { asm volatile("s_waitcnt vmcnt(0)" ::: "memory"); }
    __builtin_amdgcn_sched_barrier(0);
    __builtin_amdgcn_s_barrier();
    bi = (bi == 2) ? 0 : bi + 1;
  }

  // epilogue: merge the two k-halves. grp1 writes partials to LDS (buffers
  // are dead after the final barrier), grp0 adds + stores with residual.
  float* red = (float*)smem;       // [256][132] padded f32 = 132KB <= 144KB
  if (grp == 1){
    #pragma unroll
    for (int i = 0; i < 8; ++i)
      #pragma unroll
      for (int j = 0; j < 4; ++j)
        *(f32x4*)&red[(size_t)(br + j*16 + l16) * 132 + i*16 + q*4] = acc[i][j];
  }
  __syncthreads();
  if (grp == 0){
    const float* xb = xin + (size_t)b * CCH * NPIX;
    float* ob = outp + (size_t)b * CCH * NPIX;
    #pragma unroll
    for (int i = 0; i < 8; ++i){
      #pragma unroll
      for (int j = 0; j < 4; ++j){
        f32x4 p = *(const f32x4*)&red[(size_t)(br + j*16 + l16) * 132 + i*16 + q*4];
        int m = m0 + br + j*16 + l16;
        #pragma unroll
        for (int r2 = 0; r2 < 4; ++r2){
          int o = o0 + i*16 + q*4 + r2;
          size_t idx = (size_t)o * NPIX + m;
          ob[idx] = acc[i][j][r2] + p[r2] + xb[idx];
        }
      }
    }
  }
}

extern "C" void kernel_launch(void* const* d_in, const int* in_sizes, int n_in,
                              void* d_out, int out_size, void* d_ws, size_t ws_size,
                              hipStream_t stream){
  (void)in_sizes; (void)n_in; (void)out_size;
  const float* x  = (const float*)d_in[0];
  const float* Wq = (const float*)d_in[1];
  const float* bq = (const float*)d_in[2];
  const float* Wk = (const float*)d_in[3];
  const float* bk = (const float*)d_in[4];
  const float* Wv = (const float*)d_in[5];
  const float* bv = (const float*)d_in[6];
  const float* gm = (const float*)d_in[7];
  float* outp = (float*)d_out;

  // Workspace layout:
  char* ws = (char*)d_ws;
  u16*  Qb   = (u16*)(ws + 0);
  u16*  Kb   = (u16*)(ws + 2097152);
  u16*  Vb   = (u16*)(ws + 4194304);
  float* Z   = (float*)(ws + 20971520);
  u16*  Wqkb = (u16*)(ws + 21037056);
  u16*  Wvb  = (u16*)(ws + 21168128);
  u16*  xT   = (u16*)(ws + 21692416);

  const size_t ebytes = (size_t)NPIX * NPIX * 2;       // 33,554,432 per batch
  const size_t base   = 21692416;
  const size_t xT_end = base + (size_t)4 * NPIX * CCH * 2;   // 38,469,632
  if (ws_size < base + ebytes){
    // DIAGNOSTIC: ws too small. Harness-zeroed output -> absmax == 5.4375
    return;
  }

  hipMemsetAsync(Z, 0, (size_t)4 * NPIX * sizeof(float), stream);
  // z slices 0..3: transpose; z slice 4: weight conversion
  k0_transpose<<<dim3(64, 8, 5), 256, 0, stream>>>(x, xT, Wq, Wk, Wv, Wqkb, Wvb);
  k1_qk<<<dim3(32, 1, 4), 256, 0, stream>>>(xT, Wqkb, bq, bk, Qb, Kb);

  if (ws_size >= xT_end + 4 * ebytes){
    // No-alias path (needs 172.7 MB): E lives after xT, so k3 can run before
    // k2 and k2's epilogue folds in gamma/Z (k3b eliminated, single rounding).
    u16* E = (u16*)(ws + xT_end);
    k3_logits<<<dim3(32, 32, 4), 256, 0, stream>>>(Qb, Kb, E, Z, 0);
    k2_v<<<dim3(32, 4, 4), 256, 0, stream>>>(xT, Wvb, bv, Vb, Z, gm, 1);
    k4_out<<<dim3(16, 4, 4), 512, 0, stream>>>(Vb, E, x, outp, 0);
  } else {
    // Fallback: exact prior path. E aliases xT (xT dead after k2).
    u16* E = (u16*)(ws + base);
    int NB = 1;
    if (ws_size >= base + 4 * ebytes) NB = 4;        // >= 155.9 MB
    else if (ws_size >= base + 2 * ebytes) NB = 2;   // >=  88.8 MB
    k2_v<<<dim3(32, 4, 4), 256, 0, stream>>>(xT, Wvb, bv, Vb, Z, gm, 0);
    for (int b0 = 0; b0 < 4; b0 += NB){
      int nb = NB; if (b0 + nb > 4) nb = 4 - b0;
      k3_logits<<<dim3(32, 32, nb), 256, 0, stream>>>(Qb, Kb, E, Z, b0);
      k3b_scale<<<dim3(nb * 2048), 256, 0, stream>>>(Vb, Z, gm, b0);
      k4_out<<<dim3(16, 4, nb), 512, 0, stream>>>(Vb, E, x, outp, b0);
    }
  }
}